// Round 5
// baseline (285.838 us; speedup 1.0000x reference)
//
#include <hip/hip_runtime.h>
#include <hip/hip_cooperative_groups.h>

namespace cg = cooperative_groups;

#define NGRAPHS  256
#define GRID     256       // cooperative grid: one block per CU
#define BINR     128       // nodes per dst-range bin (bin = dst >> 7)
#define CAPB     3072      // bucket capacity per bin (mean ~2046 @ E=1.6M)
#define MAXB     1024      // max padded bins (N <= 130816)
#define NBLKC    512       // classic-path edge chunks
#define CHUNKMAX 6256      // coop: max staged edges per block (chunkE <= this)
#define NMAX     2048      // max nodes/graph in pool LDS (actual ~490)

struct SMemAC {                       // phases A (count+stage) and C (scatter)
    unsigned       stage[CHUNKMAX];   // packed (src<<7 | dst&127)
    unsigned short sbin[CHUNKMAX];    // bin id per staged edge
    int            hist[MAXB];        // histogram, then bump cursors
};
struct SMemD {                        // phase D (score)
    float acc[BINR];
};
struct SMemE {                        // phase E (top-k + pool)
    float sc[NMAX];
    int   kidx[NMAX / 2 + 64];
    float kw[NMAX / 2 + 64];
    float accs[8][64][4];
    int   pctr;
};
union SMemU { SMemAC ac; SMemD d; SMemE e; };

// =====================================================================
// Cooperative single-launch pipeline.
// A: node dots (p,r) + graph boundaries + per-block edge histogram with
//    LDS staging of packed edges.   grid.sync
// B: wave-per-bin shfl scan of C columns -> absolute bases + totals.
//    grid.sync
// C: scatter staged edges from LDS to global buckets.   grid.sync
// D: per-bin accumulate (uint4 stream + LDS f32 atomics) + tanh score.
//    grid.sync
// E: per-graph stable top-k + compacted weighted pool.
// =====================================================================
__global__ __launch_bounds__(512) void kCoop(
    const float* __restrict__ x,
    const int*   __restrict__ batch,
    const int*   __restrict__ ei,        // [2,E]: src then dst
    const float* __restrict__ w_rel,
    const float* __restrict__ w_root,
    const float* __restrict__ brel,
    float* __restrict__ p, float* __restrict__ r,
    int* __restrict__ starts, int* __restrict__ ends,
    int* __restrict__ cursor,
    int* __restrict__ C,
    unsigned* __restrict__ bucket,
    float* __restrict__ score,
    float* __restrict__ out,
    int N, int E, int chunkE, int NBINSP, int vecE)
{
    __shared__ __align__(16) SMemU sm;
    cg::grid_group grid = cg::this_grid();
    int tid = threadIdx.x;
    int blk = (int)blockIdx.x;

    // ---------------- Phase A1: dots + boundaries ----------------
    int ngrp = (N + 31) >> 5;
    for (int grp = blk; grp < ngrp; grp += GRID) {
        int row = (grp << 5) + (tid >> 4);
        int fq  = tid & 15;
        if (row < N) {
            if (fq == 0) {               // graph boundaries (handles empty graphs)
                int b = batch[row];
                if (row == 0) {
                    for (int g = 0; g < b; ++g) { starts[g] = 0; ends[g] = 0; }
                    starts[b] = 0;
                } else {
                    int bp = batch[row - 1];
                    if (bp != b) {
                        ends[bp] = row;
                        for (int g = bp + 1; g < b; ++g) { starts[g] = row; ends[g] = row; }
                        starts[b] = row;
                    }
                }
                if (row == N - 1) {
                    ends[b] = N;
                    for (int g = b + 1; g < NGRAPHS; ++g) { starts[g] = N; ends[g] = N; }
                }
            }
            float4 v  = *(const float4*)(x + (size_t)row * 64 + fq * 4);
            float4 wr = ((const float4*)w_rel)[fq];
            float4 wo = ((const float4*)w_root)[fq];
            float a = v.x * wr.x + v.y * wr.y + v.z * wr.z + v.w * wr.w;
            float c = v.x * wo.x + v.y * wo.y + v.z * wo.z + v.w * wo.w;
            a += __shfl_down(a, 8); c += __shfl_down(c, 8);
            a += __shfl_down(a, 4); c += __shfl_down(c, 4);
            a += __shfl_down(a, 2); c += __shfl_down(c, 2);
            a += __shfl_down(a, 1); c += __shfl_down(c, 1);
            if (fq == 0) { p[row] = a; r[row] = c; }
        }
    }

    // ---------------- Phase A2: count + stage this block's chunk ----------------
    for (int b = tid; b < NBINSP; b += 512) sm.ac.hist[b] = 0;
    __syncthreads();
    int beg = blk * chunkE;
    int end = min(beg + chunkE, E);
    int cnt = (end > beg) ? (end - beg) : 0;
    if (vecE) {
        const int4* s4 = (const int4*)ei;
        const int4* d4 = (const int4*)(ei + E);
        for (int i = (beg >> 2) + tid; i < (end >> 2); i += 512) {
            int4 d = d4[i];
            int4 s = s4[i];
            int o = (i << 2) - beg;
            int b0 = d.x >> 7, b1 = d.y >> 7, b2 = d.z >> 7, b3 = d.w >> 7;
            sm.ac.stage[o + 0] = ((unsigned)s.x << 7) | (unsigned)(d.x & 127);
            sm.ac.stage[o + 1] = ((unsigned)s.y << 7) | (unsigned)(d.y & 127);
            sm.ac.stage[o + 2] = ((unsigned)s.z << 7) | (unsigned)(d.z & 127);
            sm.ac.stage[o + 3] = ((unsigned)s.w << 7) | (unsigned)(d.w & 127);
            sm.ac.sbin[o + 0] = (unsigned short)b0;
            sm.ac.sbin[o + 1] = (unsigned short)b1;
            sm.ac.sbin[o + 2] = (unsigned short)b2;
            sm.ac.sbin[o + 3] = (unsigned short)b3;
            atomicAdd(&sm.ac.hist[b0], 1);
            atomicAdd(&sm.ac.hist[b1], 1);
            atomicAdd(&sm.ac.hist[b2], 1);
            atomicAdd(&sm.ac.hist[b3], 1);
        }
    } else {
        for (int i = beg + tid; i < end; i += 512) {
            int s = ei[i];
            int d = ei[E + i];
            int b = d >> 7;
            int o = i - beg;
            sm.ac.stage[o] = ((unsigned)s << 7) | (unsigned)(d & 127);
            sm.ac.sbin[o]  = (unsigned short)b;
            atomicAdd(&sm.ac.hist[b], 1);
        }
    }
    __syncthreads();
    for (int b = tid; b < NBINSP; b += 512)
        C[(size_t)blk * NBINSP + b] = sm.ac.hist[b];
    grid.sync();

    // ---------------- Phase B: wave-per-bin scan over GRID rows ----------------
    {
        int wv   = blk * 8 + (tid >> 6);     // 2048 waves >= NBINSP
        int lane = tid & 63;
        if (wv < NBINSP) {
            int b = wv;
            int v0 = C[(size_t)(lane * 4 + 0) * NBINSP + b];
            int v1 = C[(size_t)(lane * 4 + 1) * NBINSP + b];
            int v2 = C[(size_t)(lane * 4 + 2) * NBINSP + b];
            int v3 = C[(size_t)(lane * 4 + 3) * NBINSP + b];
            int s  = v0 + v1 + v2 + v3;
            int inc = s;
            #pragma unroll
            for (int off = 1; off < 64; off <<= 1) {
                int t = __shfl_up(inc, off);
                if (lane >= off) inc += t;
            }
            int run = b * CAPB + (inc - s);  // exclusive base for e = lane*4
            int c;
            c = v0; C[(size_t)(lane * 4 + 0) * NBINSP + b] = run; run += c;
            c = v1; C[(size_t)(lane * 4 + 1) * NBINSP + b] = run; run += c;
            c = v2; C[(size_t)(lane * 4 + 2) * NBINSP + b] = run; run += c;
            c = v3; C[(size_t)(lane * 4 + 3) * NBINSP + b] = run; run += c;
            if (lane == 63) cursor[b] = inc; // total count for bin
        }
    }
    grid.sync();

    // ---------------- Phase C: scatter staged edges ----------------
    for (int b = tid; b < NBINSP; b += 512)
        sm.ac.hist[b] = C[(size_t)blk * NBINSP + b];
    __syncthreads();
    for (int o = tid; o < cnt; o += 512) {
        int b   = sm.ac.sbin[o];
        int pos = atomicAdd(&sm.ac.hist[b], 1);
        if (pos < (b + 1) * CAPB) bucket[pos] = sm.ac.stage[o];
    }
    grid.sync();

    // ---------------- Phase D: per-bin accumulate + tanh score ----------------
    float bb0 = brel[0];
    for (int b = blk; b < NBINSP; b += GRID) {
        __syncthreads();
        if (tid < BINR) sm.d.acc[tid] = 0.0f;
        __syncthreads();
        int lo = b * CAPB;
        int c2 = min(cursor[b], CAPB);
        const uint4* bk4 = (const uint4*)(bucket + lo);   // CAPB%4==0 -> aligned
        int quart = c2 >> 2;
        for (int e = tid; e < quart; e += 512) {
            uint4 u = bk4[e];
            float v0 = p[u.x >> 7], v1 = p[u.y >> 7];
            float v2 = p[u.z >> 7], v3 = p[u.w >> 7];
            atomicAdd(&sm.d.acc[u.x & 127u], v0);         // ds_add_f32
            atomicAdd(&sm.d.acc[u.y & 127u], v1);
            atomicAdd(&sm.d.acc[u.z & 127u], v2);
            atomicAdd(&sm.d.acc[u.w & 127u], v3);
        }
        int tail = c2 & 3;
        if (tid < tail) {
            unsigned u = bucket[lo + (quart << 2) + tid];
            atomicAdd(&sm.d.acc[u & 127u], p[u >> 7]);
        }
        __syncthreads();
        int node = b * BINR + tid;
        if (tid < BINR && node < N)
            score[node] = tanhf(sm.d.acc[tid] + bb0 + r[node]);
    }
    grid.sync();

    // ---------------- Phase E: per-graph top-k + weighted pool ----------------
    for (int g = blk; g < NGRAPHS; g += GRID) {
        int start = starts[g];
        int n     = ends[g] - start;
        if (n > NMAX) n = NMAX;          // safety clamp (never hit)
        int k = (n + 1) >> 1;            // ceil(0.5*n) == kept count
        if (tid == 0) sm.e.pctr = 0;
        for (int i = tid; i < n; i += 512) sm.e.sc[i] = score[start + i];
        __syncthreads();

        int n4 = n & ~3;
        for (int i = tid; i < n; i += 512) {
            float si = sm.e.sc[i];
            int rank = 0;
            int j = 0;
            for (; j < n4; j += 4) {
                float4 s4 = *(const float4*)&sm.e.sc[j];
                rank += (s4.x > si) || (s4.x == si && (j + 0) < i);
                rank += (s4.y > si) || (s4.y == si && (j + 1) < i);
                rank += (s4.z > si) || (s4.z == si && (j + 2) < i);
                rank += (s4.w > si) || (s4.w == si && (j + 3) < i);
            }
            for (; j < n; ++j) {
                float sj = sm.e.sc[j];
                rank += (sj > si) || (sj == si && j < i);
            }
            if (rank < k) {
                int pos = atomicAdd(&sm.e.pctr, 1);
                sm.e.kidx[pos] = i;
                sm.e.kw[pos]   = si;
            }
        }
        __syncthreads();
        int k32 = (k + 31) & ~31;
        for (int e = k + tid; e < k32; e += 512) { sm.e.kidx[e] = 0; sm.e.kw[e] = 0.0f; }
        __syncthreads();

        int wg   = tid >> 6;
        int lane = tid & 63;
        int rgrp = lane >> 4;
        int fq   = lane & 15;
        float a0 = 0.0f, a1 = 0.0f, a2 = 0.0f, a3 = 0.0f;
        #pragma unroll 2
        for (int e = wg * 4 + rgrp; e < k32; e += 32) {
            float wv = sm.e.kw[e];
            int row  = start + sm.e.kidx[e];
            const float4 v = *(const float4*)(x + (size_t)row * 64 + fq * 4);
            a0 += v.x * wv; a1 += v.y * wv; a2 += v.z * wv; a3 += v.w * wv;
        }
        sm.e.accs[wg][lane][0] = a0; sm.e.accs[wg][lane][1] = a1;
        sm.e.accs[wg][lane][2] = a2; sm.e.accs[wg][lane][3] = a3;
        __syncthreads();
        if (tid < 64) {
            float sum = 0.0f;
            #pragma unroll
            for (int gg = 0; gg < 8; ++gg)
                #pragma unroll
                for (int rg = 0; rg < 4; ++rg)
                    sum += sm.e.accs[gg][rg * 16 + (tid >> 2)][tid & 3];
            out[(size_t)g * 64 + tid] = sum / fmaxf((float)k, 1.0f);
        }
        __syncthreads();
    }
}

// =====================================================================
// Classic multi-kernel path (fallback if cooperative launch unavailable).
// Round-0-proven structure: count -> Hillis-Steele scan -> scatter ->
// score -> pool.
// =====================================================================
__global__ __launch_bounds__(512) void k1_fused(
    const float* __restrict__ x,
    const int*   __restrict__ batch,
    const int*   __restrict__ ei,
    const float* __restrict__ w_rel,
    const float* __restrict__ w_root,
    float* __restrict__ p, float* __restrict__ r,
    int* __restrict__ starts, int* __restrict__ ends,
    int* __restrict__ C,
    int N, int E, int chunkE, int NBINSP, int vecE)
{
    __shared__ int hist[MAXB];
    int tid = threadIdx.x;

    if ((int)blockIdx.x < NBLKC) {
        if (E <= 0) return;
        for (int b = tid; b < NBINSP; b += 512) hist[b] = 0;
        __syncthreads();
        int beg = (int)blockIdx.x * chunkE;
        int end = min(beg + chunkE, E);
        if (vecE) {
            const int4* d4 = (const int4*)(ei + E);
            for (int i = (beg >> 2) + tid; i < (end >> 2); i += 512) {
                int4 d = d4[i];
                atomicAdd(&hist[d.x >> 7], 1);
                atomicAdd(&hist[d.y >> 7], 1);
                atomicAdd(&hist[d.z >> 7], 1);
                atomicAdd(&hist[d.w >> 7], 1);
            }
        } else {
            for (int i = beg + tid; i < end; i += 512)
                atomicAdd(&hist[ei[E + i] >> 7], 1);
        }
        __syncthreads();
        for (int b = tid; b < NBINSP; b += 512)
            C[(size_t)blockIdx.x * NBINSP + b] = hist[b];
        return;
    }

    int row = ((int)blockIdx.x - NBLKC) * 32 + (tid >> 4);
    int fq  = tid & 15;
    if (row >= N) return;
    if (fq == 0) {
        int b = batch[row];
        if (row == 0) {
            for (int g = 0; g < b; ++g) { starts[g] = 0; ends[g] = 0; }
            starts[b] = 0;
        } else {
            int bp = batch[row - 1];
            if (bp != b) {
                ends[bp] = row;
                for (int g = bp + 1; g < b; ++g) { starts[g] = row; ends[g] = row; }
                starts[b] = row;
            }
        }
        if (row == N - 1) {
            ends[b] = N;
            for (int g = b + 1; g < NGRAPHS; ++g) { starts[g] = N; ends[g] = N; }
        }
    }
    float4 v  = *(const float4*)(x + (size_t)row * 64 + fq * 4);
    float4 wr = ((const float4*)w_rel)[fq];
    float4 wo = ((const float4*)w_root)[fq];
    float a = v.x * wr.x + v.y * wr.y + v.z * wr.z + v.w * wr.w;
    float c = v.x * wo.x + v.y * wo.y + v.z * wo.z + v.w * wo.w;
    a += __shfl_down(a, 8); c += __shfl_down(c, 8);
    a += __shfl_down(a, 4); c += __shfl_down(c, 4);
    a += __shfl_down(a, 2); c += __shfl_down(c, 2);
    a += __shfl_down(a, 1); c += __shfl_down(c, 1);
    if (fq == 0) { p[row] = a; r[row] = c; }
}

__global__ __launch_bounds__(512) void kA2_scan(
    int* __restrict__ C, int* __restrict__ cursor, int NBLK, int NBINSP)
{
    __shared__ int sh[512];
    int b = blockIdx.x;
    int t = threadIdx.x;
    int c = (t < NBLK) ? C[(size_t)t * NBINSP + b] : 0;
    sh[t] = c;
    __syncthreads();
    #pragma unroll
    for (int off = 1; off < 512; off <<= 1) {
        int v = (t >= off) ? sh[t - off] : 0;
        __syncthreads();
        sh[t] += v;
        __syncthreads();
    }
    if (t < NBLK) C[(size_t)t * NBINSP + b] = b * CAPB + (sh[t] - c);
    if (t == 511) cursor[b] = sh[t];
}

__global__ __launch_bounds__(512) void kA3_scatter(
    const int* __restrict__ ei,
    const int* __restrict__ C,
    unsigned* __restrict__ bucket,
    int E, int chunkE, int NBINSP, int vecE)
{
    __shared__ int cur[MAXB];
    int tid = threadIdx.x;
    for (int b = tid; b < NBINSP; b += 512)
        cur[b] = C[(size_t)blockIdx.x * NBINSP + b];
    __syncthreads();
    int beg = (int)blockIdx.x * chunkE;
    int end = min(beg + chunkE, E);
    if (vecE) {
        const int4* s4 = (const int4*)ei;
        const int4* d4 = (const int4*)(ei + E);
        for (int i = (beg >> 2) + tid; i < (end >> 2); i += 512) {
            int4 d = d4[i];
            int4 s = s4[i];
            int b0 = d.x >> 7, p0 = atomicAdd(&cur[b0], 1);
            if (p0 < (b0 + 1) * CAPB) bucket[p0] = ((unsigned)s.x << 7) | (unsigned)(d.x & 127);
            int b1 = d.y >> 7, p1 = atomicAdd(&cur[b1], 1);
            if (p1 < (b1 + 1) * CAPB) bucket[p1] = ((unsigned)s.y << 7) | (unsigned)(d.y & 127);
            int b2 = d.z >> 7, p2 = atomicAdd(&cur[b2], 1);
            if (p2 < (b2 + 1) * CAPB) bucket[p2] = ((unsigned)s.z << 7) | (unsigned)(d.z & 127);
            int b3 = d.w >> 7, p3 = atomicAdd(&cur[b3], 1);
            if (p3 < (b3 + 1) * CAPB) bucket[p3] = ((unsigned)s.w << 7) | (unsigned)(d.w & 127);
        }
    } else {
        for (int i = beg + tid; i < end; i += 512) {
            int d = ei[E + i];
            int s = ei[i];
            int b = d >> 7;
            int pos = atomicAdd(&cur[b], 1);
            if (pos < (b + 1) * CAPB)
                bucket[pos] = ((unsigned)s << 7) | (unsigned)(d & 127);
        }
    }
}

__global__ __launch_bounds__(512) void kB_score(
    const unsigned* __restrict__ bucket,
    const int* __restrict__ cursor,
    const float* __restrict__ p,
    const float* __restrict__ r,
    const float* __restrict__ brel,
    float* __restrict__ score, int N)
{
    __shared__ float acc[BINR];
    int tid = threadIdx.x;
    int b   = blockIdx.x;
    if (tid < BINR) acc[tid] = 0.0f;
    __syncthreads();
    int lo  = b * CAPB;
    int cnt = min(cursor[b], CAPB);
    const uint4* bk4 = (const uint4*)(bucket + lo);
    int quart = cnt >> 2;
    for (int e = tid; e < quart; e += 512) {
        uint4 u = bk4[e];
        float v0 = p[u.x >> 7], v1 = p[u.y >> 7];
        float v2 = p[u.z >> 7], v3 = p[u.w >> 7];
        atomicAdd(&acc[u.x & 127u], v0);
        atomicAdd(&acc[u.y & 127u], v1);
        atomicAdd(&acc[u.z & 127u], v2);
        atomicAdd(&acc[u.w & 127u], v3);
    }
    int tail = cnt & 3;
    if (tid < tail) {
        unsigned u = bucket[lo + (quart << 2) + tid];
        atomicAdd(&acc[u & 127u], p[u >> 7]);
    }
    __syncthreads();
    int node = b * BINR + tid;
    if (tid < BINR && node < N)
        score[node] = tanhf(acc[tid] + brel[0] + r[node]);
}

__global__ __launch_bounds__(256) void kZ_zero(float* __restrict__ a, int N)
{
    int i = blockIdx.x * 256 + threadIdx.x;
    if (i < N) a[i] = 0.0f;
}
__global__ __launch_bounds__(256) void k2_scatter(
    const int* __restrict__ ei, const float* __restrict__ p,
    float* aggdot, int E)
{
    int i = blockIdx.x * 256 + threadIdx.x;
    if (i < E) unsafeAtomicAdd(&aggdot[ei[E + i]], p[ei[i]]);
}
__global__ __launch_bounds__(256) void kS_score(
    const float* __restrict__ aggdot, const float* __restrict__ r,
    const float* __restrict__ brel, float* __restrict__ score, int N)
{
    int i = blockIdx.x * 256 + threadIdx.x;
    if (i < N) score[i] = tanhf(aggdot[i] + brel[0] + r[i]);
}

__global__ __launch_bounds__(512) void k4_pool(
    const float* __restrict__ x,
    const float* __restrict__ score,
    const int* __restrict__ starts,
    const int* __restrict__ ends,
    float* __restrict__ out)
{
    __shared__ __align__(16) float sc[NMAX];
    __shared__ int   kidx[NMAX / 2 + 64];
    __shared__ float kw[NMAX / 2 + 64];
    __shared__ float accs[8][64][4];
    __shared__ int   pctr;

    int g   = blockIdx.x;
    int tid = threadIdx.x;
    int start = starts[g];
    int n     = ends[g] - start;
    if (n > NMAX) n = NMAX;
    int k = (n + 1) >> 1;
    if (tid == 0) pctr = 0;

    for (int i = tid; i < n; i += 512) sc[i] = score[start + i];
    __syncthreads();

    int n4 = n & ~3;
    for (int i = tid; i < n; i += 512) {
        float si = sc[i];
        int rank = 0;
        int j = 0;
        for (; j < n4; j += 4) {
            float4 s4 = *(const float4*)&sc[j];
            rank += (s4.x > si) || (s4.x == si && (j + 0) < i);
            rank += (s4.y > si) || (s4.y == si && (j + 1) < i);
            rank += (s4.z > si) || (s4.z == si && (j + 2) < i);
            rank += (s4.w > si) || (s4.w == si && (j + 3) < i);
        }
        for (; j < n; ++j) {
            float sj = sc[j];
            rank += (sj > si) || (sj == si && j < i);
        }
        if (rank < k) {
            int pos = atomicAdd(&pctr, 1);
            kidx[pos] = i;
            kw[pos]   = si;
        }
    }
    __syncthreads();
    int k32 = (k + 31) & ~31;
    for (int e = k + tid; e < k32; e += 512) { kidx[e] = 0; kw[e] = 0.0f; }
    __syncthreads();

    int wg   = tid >> 6;
    int lane = tid & 63;
    int rgrp = lane >> 4;
    int fq   = lane & 15;
    float a0 = 0.0f, a1 = 0.0f, a2 = 0.0f, a3 = 0.0f;
    #pragma unroll 2
    for (int e = wg * 4 + rgrp; e < k32; e += 32) {
        float wv = kw[e];
        int row  = start + kidx[e];
        const float4 v = *(const float4*)(x + (size_t)row * 64 + fq * 4);
        a0 += v.x * wv; a1 += v.y * wv; a2 += v.z * wv; a3 += v.w * wv;
    }
    accs[wg][lane][0] = a0; accs[wg][lane][1] = a1;
    accs[wg][lane][2] = a2; accs[wg][lane][3] = a3;
    __syncthreads();
    if (tid < 64) {
        float sum = 0.0f;
        #pragma unroll
        for (int gg = 0; gg < 8; ++gg)
            #pragma unroll
            for (int rg = 0; rg < 4; ++rg)
                sum += accs[gg][rg * 16 + (tid >> 2)][tid & 3];
        out[(size_t)g * 64 + tid] = sum / fmaxf((float)k, 1.0f);
    }
}

extern "C" void kernel_launch(void* const* d_in, const int* in_sizes, int n_in,
                              void* d_out, int out_size, void* d_ws, size_t ws_size,
                              hipStream_t stream) {
    const float* x      = (const float*)d_in[0];
    const int*   ei     = (const int*)  d_in[1];
    const int*   batch  = (const int*)  d_in[2];
    const float* w_rel  = (const float*)d_in[3];
    const float* b_rel  = (const float*)d_in[4];
    const float* w_root = (const float*)d_in[5];
    float* out = (float*)d_out;

    int N = in_sizes[2];
    int E = in_sizes[1] / 2;
    int NBINS  = (N + BINR - 1) / BINR;
    int NBINSP = (NBINS + 15) & ~15;
    int vecE   = ((E & 3) == 0);
    int dotblks = (N + 31) / 32;

    // ws layout (4B units): p[N], r[N], score[N], starts[256], ends[256],
    // cursor[MAXB], C[max(NBLKC,GRID)*NBINSP], bucket u32[NBINSP*CAPB]
    float* p      = (float*)d_ws;
    float* r      = p + (size_t)N;
    float* score  = r + (size_t)N;
    int*   starts = (int*)(score + (size_t)N);
    int*   ends   = starts + NGRAPHS;
    int*   cursor = ends + NGRAPHS;
    int*   C      = cursor + MAXB;
    size_t crows  = (NBLKC > GRID) ? NBLKC : GRID;
    size_t boff = (size_t)3 * N + 2 * NGRAPHS + MAXB + crows * NBINSP;
    boff = (boff + 3) & ~(size_t)3;
    unsigned* bucket = (unsigned*)d_ws + boff;
    size_t need = (boff + (size_t)NBINSP * CAPB) * 4;

    bool binned = (need <= ws_size) && (NBINSP <= MAXB) && (N <= (1 << 24));

    // ---- cooperative single-launch path ----
    int chunkEc = (((E + GRID - 1) / GRID) + 3) & ~3;
    if (binned && chunkEc <= CHUNKMAX && E > 0) {
        void* args[] = {
            (void*)&x, (void*)&batch, (void*)&ei, (void*)&w_rel, (void*)&w_root,
            (void*)&b_rel, (void*)&p, (void*)&r, (void*)&starts, (void*)&ends,
            (void*)&cursor, (void*)&C, (void*)&bucket, (void*)&score, (void*)&out,
            (void*)&N, (void*)&E, (void*)&chunkEc, (void*)&NBINSP, (void*)&vecE };
        hipError_t rc = hipLaunchCooperativeKernel(
            (const void*)kCoop, dim3(GRID), dim3(512), args, 0, stream);
        if (rc == hipSuccess) return;
        (void)hipGetLastError();         // clear error, fall through to classic
    }

    // ---- classic multi-kernel path ----
    int chunkE = (((E + NBLKC - 1) / NBLKC) + 3) & ~3;
    if (binned) {
        k1_fused<<<NBLKC + dotblks, 512, 0, stream>>>(
            x, batch, ei, w_rel, w_root, p, r, starts, ends, C,
            N, E, chunkE, NBINSP, vecE);
        kA2_scan<<<NBINSP, 512, 0, stream>>>(C, cursor, NBLKC, NBINSP);
        kA3_scatter<<<NBLKC, 512, 0, stream>>>(ei, C, bucket, E, chunkE, NBINSP, vecE);
        kB_score<<<NBINS, 512, 0, stream>>>(bucket, cursor, p, r, b_rel, score, N);
    } else {
        float* aggdot = (float*)C;
        k1_fused<<<NBLKC + dotblks, 512, 0, stream>>>(
            x, batch, ei, w_rel, w_root, p, r, starts, ends, C,
            N, 0, 0, NBINSP, vecE);
        kZ_zero<<<(N + 255) / 256, 256, 0, stream>>>(aggdot, N);
        k2_scatter<<<(E + 255) / 256, 256, 0, stream>>>(ei, p, aggdot, E);
        kS_score<<<(N + 255) / 256, 256, 0, stream>>>(aggdot, r, b_rel, score, N);
    }
    k4_pool<<<NGRAPHS, 512, 0, stream>>>(x, score, starts, ends, out);
}

// Round 6
// 137.197 us; speedup vs baseline: 2.0834x; 2.0834x over previous
//
#include <hip/hip_runtime.h>

#define NGRAPHS 256
#define BINR   128        // nodes per dst-range bin (bin = dst >> 7)
#define CAPB   3072       // bucket capacity per bin (mean ~2046 @ E=1.6M)
#define MAXB   1024       // max padded bins (N <= 130816)
#define SBLK   512        // scatter blocks (chunk = ceil(E/SBLK))
#define CHUNKS 3328       // max staged edges per scatter block
#define NMAX   2048       // max nodes/graph in pool LDS (actual ~490)

// =====================================================================
// kA: role-split single kernel.
//   Blocks [0,SBLK): LDS-stage packed edges + LDS histogram -> one global
//     atomicAdd per (block,bin) reserves a bucket range -> scatter from LDS.
//     (replaces count kernel + scan kernel; bucket order within a bin is
//      irrelevant since kB only sums)
//   Blocks [SBLK,...): float4 node dots (32 rows/block) + graph boundaries.
// cursor[] must be zeroed before launch (hipMemsetAsync).
// =====================================================================
__global__ __launch_bounds__(512) void kA_fused(
    const float* __restrict__ x,
    const int*   __restrict__ batch,
    const int*   __restrict__ ei,        // [2,E]: src then dst
    const float* __restrict__ w_rel,
    const float* __restrict__ w_root,
    float* __restrict__ p, float* __restrict__ r,
    int* __restrict__ starts, int* __restrict__ ends,
    int* __restrict__ cursor,            // [MAXB], pre-zeroed; ends as totals
    unsigned* __restrict__ bucket,
    int N, int E, int chunkE, int NBINSP, int vecE)
{
    __shared__ __align__(16) unsigned stage[CHUNKS];
    __shared__ unsigned short sbin[CHUNKS];
    __shared__ int hist[MAXB];           // histogram, then running write cursor
    int tid = threadIdx.x;

    if ((int)blockIdx.x < SBLK) {        // ---- scatter role ----
        if (E <= 0) return;              // fallback path: role disabled
        for (int b = tid; b < NBINSP; b += 512) hist[b] = 0;
        __syncthreads();
        int beg = (int)blockIdx.x * chunkE;
        int end = min(beg + chunkE, E);
        int cnt = (end > beg) ? (end - beg) : 0;
        if (vecE) {
            const int4* s4 = (const int4*)ei;
            const int4* d4 = (const int4*)(ei + E);
            for (int i = (beg >> 2) + tid; i < (end >> 2); i += 512) {
                int4 d = d4[i];
                int4 s = s4[i];
                int o = (i << 2) - beg;
                int b0 = d.x >> 7, b1 = d.y >> 7, b2 = d.z >> 7, b3 = d.w >> 7;
                stage[o + 0] = ((unsigned)s.x << 7) | (unsigned)(d.x & 127);
                stage[o + 1] = ((unsigned)s.y << 7) | (unsigned)(d.y & 127);
                stage[o + 2] = ((unsigned)s.z << 7) | (unsigned)(d.z & 127);
                stage[o + 3] = ((unsigned)s.w << 7) | (unsigned)(d.w & 127);
                sbin[o + 0] = (unsigned short)b0;
                sbin[o + 1] = (unsigned short)b1;
                sbin[o + 2] = (unsigned short)b2;
                sbin[o + 3] = (unsigned short)b3;
                atomicAdd(&hist[b0], 1);
                atomicAdd(&hist[b1], 1);
                atomicAdd(&hist[b2], 1);
                atomicAdd(&hist[b3], 1);
            }
        } else {
            for (int i = beg + tid; i < end; i += 512) {
                int s = ei[i];
                int d = ei[E + i];
                int b = d >> 7;
                int o = i - beg;
                stage[o] = ((unsigned)s << 7) | (unsigned)(d & 127);
                sbin[o]  = (unsigned short)b;
                atomicAdd(&hist[b], 1);
            }
        }
        __syncthreads();
        // reserve output ranges: one global atomic per touched bin
        for (int b = tid; b < NBINSP; b += 512) {
            int h = hist[b];
            hist[b] = (h > 0) ? b * CAPB + atomicAdd(&cursor[b], h) : 0;
        }
        __syncthreads();
        // scatter staged edges (hist[] now = running global cursor per bin)
        for (int o = tid; o < cnt; o += 512) {
            int b   = sbin[o];
            int pos = atomicAdd(&hist[b], 1);
            if (pos < (b + 1) * CAPB) bucket[pos] = stage[o];
        }
        return;
    }

    // ---- node-dot role: 32 rows/block, 16 lanes/row, float4/lane ----
    int row = ((int)blockIdx.x - SBLK) * 32 + (tid >> 4);
    int fq  = tid & 15;
    if (row >= N) return;
    if (fq == 0) {                       // graph boundaries (handles empty graphs)
        int b = batch[row];
        if (row == 0) {
            for (int g = 0; g < b; ++g) { starts[g] = 0; ends[g] = 0; }
            starts[b] = 0;
        } else {
            int bp = batch[row - 1];
            if (bp != b) {
                ends[bp] = row;
                for (int g = bp + 1; g < b; ++g) { starts[g] = row; ends[g] = row; }
                starts[b] = row;
            }
        }
        if (row == N - 1) {
            ends[b] = N;
            for (int g = b + 1; g < NGRAPHS; ++g) { starts[g] = N; ends[g] = N; }
        }
    }
    float4 v  = *(const float4*)(x + (size_t)row * 64 + fq * 4);
    float4 wr = ((const float4*)w_rel)[fq];
    float4 wo = ((const float4*)w_root)[fq];
    float a = v.x * wr.x + v.y * wr.y + v.z * wr.z + v.w * wr.w;
    float c = v.x * wo.x + v.y * wo.y + v.z * wo.z + v.w * wo.w;
    a += __shfl_down(a, 8); c += __shfl_down(c, 8);
    a += __shfl_down(a, 4); c += __shfl_down(c, 4);
    a += __shfl_down(a, 2); c += __shfl_down(c, 2);
    a += __shfl_down(a, 1); c += __shfl_down(c, 1);
    if (fq == 0) { p[row] = a; r[row] = c; }
}

// ---- kB: one block per bin. uint4 bucket stream, p gather (L2), LDS f32
//      atomics into acc[128], fused tanh -> final per-node score. ----
__global__ __launch_bounds__(512) void kB_score(
    const unsigned* __restrict__ bucket,
    const int* __restrict__ cursor,
    const float* __restrict__ p,
    const float* __restrict__ r,
    const float* __restrict__ brel,
    float* __restrict__ score, int N)
{
    __shared__ float acc[BINR];
    int tid = threadIdx.x;
    int b   = blockIdx.x;
    if (tid < BINR) acc[tid] = 0.0f;
    __syncthreads();
    int lo  = b * CAPB;
    int cnt = min(cursor[b], CAPB);
    const uint4* bk4 = (const uint4*)(bucket + lo);   // CAPB % 4 == 0 -> aligned
    int quart = cnt >> 2;
    for (int e = tid; e < quart; e += 512) {
        uint4 u = bk4[e];
        float v0 = p[u.x >> 7], v1 = p[u.y >> 7];
        float v2 = p[u.z >> 7], v3 = p[u.w >> 7];
        atomicAdd(&acc[u.x & 127u], v0);              // ds_add_f32
        atomicAdd(&acc[u.y & 127u], v1);
        atomicAdd(&acc[u.z & 127u], v2);
        atomicAdd(&acc[u.w & 127u], v3);
    }
    int tail = cnt & 3;
    if (tid < tail) {
        unsigned u = bucket[lo + (quart << 2) + tid];
        atomicAdd(&acc[u & 127u], p[u >> 7]);
    }
    __syncthreads();
    int node = b * BINR + tid;
    if (tid < BINR && node < N)
        score[node] = tanhf(acc[tid] + brel[0] + r[node]);
}

// ---- fallback (guards fail): zero + device-scope atomic scatter + score ----
__global__ __launch_bounds__(256) void kZ_zero(float* __restrict__ a, int N)
{
    int i = blockIdx.x * 256 + threadIdx.x;
    if (i < N) a[i] = 0.0f;
}
__global__ __launch_bounds__(256) void k2_scatter(
    const int* __restrict__ ei, const float* __restrict__ p,
    float* aggdot, int E)
{
    int i = blockIdx.x * 256 + threadIdx.x;
    if (i < E) unsafeAtomicAdd(&aggdot[ei[E + i]], p[ei[i]]);
}
__global__ __launch_bounds__(256) void kS_score(
    const float* __restrict__ aggdot, const float* __restrict__ r,
    const float* __restrict__ brel, float* __restrict__ score, int N)
{
    int i = blockIdx.x * 256 + threadIdx.x;
    if (i < N) score[i] = tanhf(aggdot[i] + brel[0] + r[i]);
}

// ---- k4: per-graph stable top-k rank (float4 LDS j-loop) + compacted
//      float4 weighted pool ----
__global__ __launch_bounds__(512) void k4_pool(
    const float* __restrict__ x,
    const float* __restrict__ score,
    const int* __restrict__ starts,
    const int* __restrict__ ends,
    float* __restrict__ out)
{
    __shared__ __align__(16) float sc[NMAX];
    __shared__ int   kidx[NMAX / 2 + 64];
    __shared__ float kw[NMAX / 2 + 64];
    __shared__ float accs[8][64][4];
    __shared__ int   pctr;

    int g   = blockIdx.x;
    int tid = threadIdx.x;
    int start = starts[g];
    int n     = ends[g] - start;
    if (n > NMAX) n = NMAX;              // safety clamp (never hit)
    int k = (n + 1) >> 1;                // ceil(0.5*n) == kept count
    if (tid == 0) pctr = 0;

    for (int i = tid; i < n; i += 512) sc[i] = score[start + i];
    __syncthreads();

    // stable rank (lexsort tie-break: score desc, index asc) + compaction
    int n4 = n & ~3;
    for (int i = tid; i < n; i += 512) {
        float si = sc[i];
        int rank = 0;
        int j = 0;
        for (; j < n4; j += 4) {
            float4 s4 = *(const float4*)&sc[j];
            rank += (s4.x > si) || (s4.x == si && (j + 0) < i);
            rank += (s4.y > si) || (s4.y == si && (j + 1) < i);
            rank += (s4.z > si) || (s4.z == si && (j + 2) < i);
            rank += (s4.w > si) || (s4.w == si && (j + 3) < i);
        }
        for (; j < n; ++j) {
            float sj = sc[j];
            rank += (sj > si) || (sj == si && j < i);
        }
        if (rank < k) {
            int pos = atomicAdd(&pctr, 1);
            kidx[pos] = i;
            kw[pos]   = si;
        }
    }
    __syncthreads();
    int k32 = (k + 31) & ~31;
    for (int e = k + tid; e < k32; e += 512) { kidx[e] = 0; kw[e] = 0.0f; }
    __syncthreads();

    // weighted pool over compacted kept list: each 16-lane group reads one
    // contiguous 256B row
    int wg   = tid >> 6;
    int lane = tid & 63;
    int rgrp = lane >> 4;
    int fq   = lane & 15;
    float a0 = 0.0f, a1 = 0.0f, a2 = 0.0f, a3 = 0.0f;
    #pragma unroll 2
    for (int e = wg * 4 + rgrp; e < k32; e += 32) {
        float wv = kw[e];
        int row  = start + kidx[e];
        const float4 v = *(const float4*)(x + (size_t)row * 64 + fq * 4);
        a0 += v.x * wv; a1 += v.y * wv; a2 += v.z * wv; a3 += v.w * wv;
    }
    accs[wg][lane][0] = a0; accs[wg][lane][1] = a1;
    accs[wg][lane][2] = a2; accs[wg][lane][3] = a3;
    __syncthreads();
    if (tid < 64) {
        float sum = 0.0f;
        #pragma unroll
        for (int gg = 0; gg < 8; ++gg)
            #pragma unroll
            for (int rg = 0; rg < 4; ++rg)
                sum += accs[gg][rg * 16 + (tid >> 2)][tid & 3];
        out[(size_t)g * 64 + tid] = sum / fmaxf((float)k, 1.0f);
    }
}

extern "C" void kernel_launch(void* const* d_in, const int* in_sizes, int n_in,
                              void* d_out, int out_size, void* d_ws, size_t ws_size,
                              hipStream_t stream) {
    const float* x      = (const float*)d_in[0];
    const int*   ei     = (const int*)  d_in[1];
    const int*   batch  = (const int*)  d_in[2];
    const float* w_rel  = (const float*)d_in[3];
    const float* b_rel  = (const float*)d_in[4];
    const float* w_root = (const float*)d_in[5];
    float* out = (float*)d_out;

    int N = in_sizes[2];
    int E = in_sizes[1] / 2;
    int NBINS  = (N + BINR - 1) / BINR;
    int NBINSP = (NBINS + 15) & ~15;
    int chunkE = (((E + SBLK - 1) / SBLK) + 3) & ~3;
    int vecE   = ((E & 3) == 0);
    int dotblks = (N + 31) / 32;

    // ws layout (4B units): p[N], r[N], score[N], starts[256], ends[256],
    // cursor[MAXB], (align16) bucket u32[NBINSP*CAPB]
    float* p      = (float*)d_ws;
    float* r      = p + (size_t)N;
    float* score  = r + (size_t)N;
    int*   starts = (int*)(score + (size_t)N);
    int*   ends   = starts + NGRAPHS;
    int*   cursor = ends + NGRAPHS;
    size_t boff = (size_t)3 * N + 2 * NGRAPHS + MAXB;
    boff = (boff + 3) & ~(size_t)3;                  // 16B-align bucket
    unsigned* bucket = (unsigned*)d_ws + boff;
    size_t need = (boff + (size_t)NBINSP * CAPB) * 4;

    bool binned = (need <= ws_size) && (NBINSP <= MAXB)
                  && (chunkE <= CHUNKS) && (N <= (1 << 24)) && (E > 0);

    if (binned) {
        hipMemsetAsync(cursor, 0, MAXB * sizeof(int), stream);
        kA_fused<<<SBLK + dotblks, 512, 0, stream>>>(
            x, batch, ei, w_rel, w_root, p, r, starts, ends, cursor, bucket,
            N, E, chunkE, NBINSP, vecE);
        kB_score<<<NBINS, 512, 0, stream>>>(bucket, cursor, p, r, b_rel, score, N);
    } else {
        float* aggdot = (float*)bucket;  // fallback-only alias
        kA_fused<<<SBLK + dotblks, 512, 0, stream>>>(
            x, batch, ei, w_rel, w_root, p, r, starts, ends, cursor, bucket,
            N, 0, 0, NBINSP, vecE);      // E=0: scatter blocks exit immediately
        kZ_zero<<<(N + 255) / 256, 256, 0, stream>>>(aggdot, N);
        k2_scatter<<<(E + 255) / 256, 256, 0, stream>>>(ei, p, aggdot, E);
        kS_score<<<(N + 255) / 256, 256, 0, stream>>>(aggdot, r, b_rel, score, N);
    }
    k4_pool<<<NGRAPHS, 512, 0, stream>>>(x, score, starts, ends, out);
}